// Round 3
// baseline (43.763 us; speedup 1.0000x reference)
//
#include <hip/hip_runtime.h>
#include <hip/hip_bf16.h>

typedef __attribute__((ext_vector_type(8))) short  short8_t;
typedef __attribute__((ext_vector_type(4))) float  float4_t;
typedef __attribute__((ext_vector_type(4))) int    int4_t;
typedef __attribute__((ext_vector_type(2))) unsigned int uint2_t;

#define BM 64
#define BN 128
#define BK 64
#define HSTR 72      // hs row stride (144 B): 2-way on b128 reads (free)
#define NCHUNK 16

__device__ __forceinline__ unsigned short f2bf(float f) {
    unsigned int u = __builtin_bit_cast(unsigned int, f);
    u += 0x7FFFu + ((u >> 16) & 1u);          // RNE
    return (unsigned short)(u >> 16);
}
__device__ __forceinline__ unsigned int pack2(float a, float b) {
    return (unsigned int)f2bf(a) | ((unsigned int)f2bf(b) << 16);
}
__device__ __forceinline__ void gload_lds16(const void* g, void* l) {
    __builtin_amdgcn_global_load_lds(
        (const __attribute__((address_space(1))) void*)g,
        (__attribute__((address_space(3))) void*)l, 16, 0, 0);
}

// ---- pre-pass: f32 -> bf16 (4 elems/thread) ----
__global__ void cvt_kernel(const float* __restrict__ src, unsigned short* __restrict__ dst) {
    const int i = (blockIdx.x * blockDim.x + threadIdx.x) * 4;
    const float4_t v = *reinterpret_cast<const float4_t*>(src + i);
    unsigned long long p = (unsigned long long)pack2(v[0], v[1])
                         | ((unsigned long long)pack2(v[2], v[3]) << 32);
    *reinterpret_cast<unsigned long long*>(dst + i) = p;
}

// fused: q=cos(x[:,:8])*cos(theta) -> h=relu(q@W1^T) (MFMA, LDS-only) -> out=h@W2^T (MFMA)
// Pipeline: double-buffered Bs+hs, ONE __syncthreads per K-chunk; staging for chunk k+1
// issued right after barrier(k), drained by barrier(k+1) => global latency hidden under MFMA.
template <bool WSOK>
__global__ __launch_bounds__(256, 3)
void ffq_kernel(const float* __restrict__ x,
                const float* __restrict__ theta,
                const float* __restrict__ W1f,
                const unsigned short* __restrict__ W1b,
                const float* __restrict__ W2f,
                const unsigned short* __restrict__ W2b,
                float* __restrict__ out)
{
    __shared__ __align__(16) unsigned short qs[BM][8];            //  1 KB
    __shared__ __align__(16) unsigned short hs[2][BM][HSTR];      // 18 KB
    __shared__ __align__(16) unsigned short Bs[2][BN][BK];        // 32 KB (XOR-swizzled slots)

    const int tid  = threadIdx.x;
    const int lane = tid & 63;
    const int w    = tid >> 6;            // wave 0..3
    const int bid  = blockIdx.x;
    const int rowbase = (bid >> 1) * BM;
    const int colbase = (bid & 1) * BN;

    // ---- q prologue: wave 0 computes q[64][8] -> LDS (bf16) ----
    if (w == 0) {
        const float* xp = x + (size_t)(rowbase + lane) * 256;
        const float4_t x0 = *reinterpret_cast<const float4_t*>(xp);
        const float4_t x1 = *reinterpret_cast<const float4_t*>(xp + 4);
        float qv[8];
        #pragma unroll
        for (int j = 0; j < 4; ++j) {
            qv[j]     = __cosf(x0[j]) * __cosf(theta[j]);
            qv[4 + j] = __cosf(x1[j]) * __cosf(theta[4 + j]);
        }
        int4_t pq;
        pq[0] = (int)pack2(qv[0], qv[1]);
        pq[1] = (int)pack2(qv[2], qv[3]);
        pq[2] = (int)pack2(qv[4], qv[5]);
        pq[3] = (int)pack2(qv[6], qv[7]);
        *reinterpret_cast<int4_t*>(&qs[lane][0]) = pq;
    }
    __syncthreads();

    // ---- hoist q B-frags (one per 16-row m-tile); data in k-group-0 lanes, rest zero ----
    short8_t qf[4];
    #pragma unroll
    for (int mt = 0; mt < 4; ++mt) {
        short8_t v = {0, 0, 0, 0, 0, 0, 0, 0};
        if (lane < 16) v = *reinterpret_cast<const short8_t*>(&qs[mt * 16 + lane][0]);
        qf[mt] = v;
    }

    float4_t acc[2][4];
    #pragma unroll
    for (int i = 0; i < 2; ++i)
        #pragma unroll
        for (int j = 0; j < 4; ++j)
            acc[i][j] = (float4_t){0.f, 0.f, 0.f, 0.f};

    const int lr  = lane & 15;
    const int lkg = lane >> 4;            // 0..3
    const int lk  = lkg * 8;
    const int er  = lane >> 3;            // 0..7 (row within an 8-row DMA group)
    const int js  = lane & 7;             // 16B slot within a 128B row
    const int wr  = w >> 1, wc = w & 1;

    // ---- staging: W2 chunk -> Bs[buf] (swizzled slots; linear LDS dest for DMA) ----
    auto stage = [&](int buf, int kc) {
        #pragma unroll
        for (int it = 0; it < 4; ++it) {
            const int e = w * 32 + it * 8 + er;
            const int srccol = ((js ^ (e & 7)) << 3);   // pre-swizzled global source
            if constexpr (WSOK) {
                gload_lds16(W2b + (size_t)(colbase + e) * 1024 + kc + srccol,
                            &Bs[buf][w * 32 + it * 8][0]);
            } else {
                const float* src = W2f + (size_t)(colbase + e) * 1024 + kc + srccol;
                const float4_t v0 = *reinterpret_cast<const float4_t*>(src);
                const float4_t v1 = *reinterpret_cast<const float4_t*>(src + 4);
                int4_t p;
                p[0] = (int)pack2(v0[0], v0[1]);
                p[1] = (int)pack2(v0[2], v0[3]);
                p[2] = (int)pack2(v1[0], v1[1]);
                p[3] = (int)pack2(v1[2], v1[3]);
                *reinterpret_cast<int4_t*>(&Bs[buf][e][js * 8]) = p;
            }
        }
    };

    // ---- W1 A-frag for this wave's 16 f-rows of a chunk (K=8 zero-padded to 32) ----
    auto load_af = [&](int kc) -> short8_t {
        short8_t af = {0, 0, 0, 0, 0, 0, 0, 0};
        if (lane < 16) {
            if constexpr (WSOK) {
                af = *reinterpret_cast<const short8_t*>(W1b + (size_t)(kc + w * 16 + lane) * 8);
            } else {
                const float* src = W1f + (size_t)(kc + w * 16 + lane) * 8;
                const float4_t v0 = *reinterpret_cast<const float4_t*>(src);
                const float4_t v1 = *reinterpret_cast<const float4_t*>(src + 4);
                int4_t p;
                p[0] = (int)pack2(v0[0], v0[1]);
                p[1] = (int)pack2(v0[2], v0[3]);
                p[2] = (int)pack2(v1[0], v1[1]);
                p[3] = (int)pack2(v1[2], v1[3]);
                af = __builtin_bit_cast(short8_t, p);
            }
        }
        return af;
    };

    // ---- h-phase: D[f][m] = W1 x q^T; relu; pack into regs (written to hs next iter) ----
    uint2_t pk[4];
    auto hcompute = [&](short8_t af) {
        #pragma unroll
        for (int mt = 0; mt < 4; ++mt) {
            float4_t d = __builtin_amdgcn_mfma_f32_16x16x32_bf16(
                af, qf[mt], (float4_t){0.f, 0.f, 0.f, 0.f}, 0, 0, 0);
            pk[mt][0] = pack2(fmaxf(d[0], 0.f), fmaxf(d[1], 0.f));
            pk[mt][1] = pack2(fmaxf(d[2], 0.f), fmaxf(d[3], 0.f));
        }
    };

    // ---- prologue: chunk 0 staging + h0 in regs ----
    stage(0, 0);
    hcompute(load_af(0));

    for (int k = 0; k < NCHUNK; ++k) {
        const int cur = k & 1, nxt = cur ^ 1;

        // write hs[cur] (buffer last read in iter k-2; free)
        #pragma unroll
        for (int mt = 0; mt < 4; ++mt)
            *reinterpret_cast<uint2_t*>(&hs[cur][mt * 16 + lr][w * 16 + lkg * 4]) = pk[mt];

        __syncthreads();   // drains Bs[cur] staging (issued iter k-1) + publishes hs[cur]

        short8_t afn;
        if (k + 1 < NCHUNK) {
            stage(nxt, (k + 1) * BK);       // in flight during main MFMA below
            afn = load_af((k + 1) * BK);    // L2-resident; latency hidden under MFMA
        }

        // main MFMA: each wave 32 rows x 64 cols over K=64
        #pragma unroll
        for (int kk = 0; kk < BK; kk += 32) {
            const short8_t a0 = *reinterpret_cast<const short8_t*>(
                &hs[cur][wr * 32 + 0  + lr][kk + lk]);
            const short8_t a1 = *reinterpret_cast<const short8_t*>(
                &hs[cur][wr * 32 + 16 + lr][kk + lk]);
            const int s = (kk + lk) >> 3;
            #pragma unroll
            for (int cf = 0; cf < 4; ++cf) {
                const int e = wc * 64 + cf * 16 + lr;
                const short8_t b = *reinterpret_cast<const short8_t*>(
                    &Bs[cur][e][(s ^ (e & 7)) << 3]);
                acc[0][cf] = __builtin_amdgcn_mfma_f32_16x16x32_bf16(a0, b, acc[0][cf], 0, 0, 0);
                acc[1][cf] = __builtin_amdgcn_mfma_f32_16x16x32_bf16(a1, b, acc[1][cf], 0, 0, 0);
            }
        }

        if (k + 1 < NCHUNK) hcompute(afn);  // h for next chunk, overlaps tail
    }

    // ---- epilogue: C/D layout col=lane&15, row=(lane>>4)*4+reg ----
    const int lq = lane >> 4;
    #pragma unroll
    for (int rf = 0; rf < 2; ++rf) {
        #pragma unroll
        for (int cf = 0; cf < 4; ++cf) {
            #pragma unroll
            for (int r = 0; r < 4; ++r) {
                const int gr = rowbase + wr * 32 + rf * 16 + lq * 4 + r;
                const int gc = colbase + wc * 64 + cf * 16 + lr;
                out[(size_t)gr * 256 + gc] = acc[rf][cf][r];
            }
        }
    }
}

extern "C" void kernel_launch(void* const* d_in, const int* in_sizes, int n_in,
                              void* d_out, int out_size, void* d_ws, size_t ws_size,
                              hipStream_t stream) {
    const float* x     = (const float*)d_in[0];   // [8,4096,256]
    const float* theta = (const float*)d_in[1];   // [8]
    const float* W1    = (const float*)d_in[2];   // [1024,8]
    const float* W2    = (const float*)d_in[3];   // [256,1024]
    float* out = (float*)d_out;                   // [8,4096,256] f32

    const size_t need = (size_t)(256 * 1024 + 8 * 1024) * sizeof(unsigned short);
    const bool wsok = (ws_size >= need);

    if (wsok) {
        unsigned short* W2b = (unsigned short*)d_ws;          // 256*1024 bf16
        unsigned short* W1b = W2b + 256 * 1024;               // 1024*8 bf16
        cvt_kernel<<<256, 256, 0, stream>>>(W2, W2b);
        cvt_kernel<<<8,   256, 0, stream>>>(W1, W1b);
        ffq_kernel<true><<<1024, 256, 0, stream>>>(x, theta, nullptr, W1b, nullptr, W2b, out);
    } else {
        ffq_kernel<false><<<1024, 256, 0, stream>>>(x, theta, W1, nullptr, W2, nullptr, out);
    }
}